// Round 11
// baseline (1609.088 us; speedup 1.0000x reference)
//
#include <hip/hip_runtime.h>
#include <hip/hip_bf16.h>
#include <cmath>

#define HID 150
#define NN 100000
#define NE 1600000
#define NL 5
#define NP 640              // padded N: 4 sections x 160 (r, z, i_n, h_n)
#define KP 320              // B K-coords: [aggr 0..149 | bias 150 | pad | h 160..309 | pad]
#define KS 10               // k-steps of 32
#define BM 64               // rows per block
#define HSTEPS 20           // half-k-steps (ks x {sec01, sec23})
#define HS_BF (20*64*8)     // bf16 per half-step chunk = 10240 (20 KB)
#define HROW 160            // bf16 per h row (150 + 10 pad)

// bucketed CSR build (LDS-binned two-phase counting sort)
#define NPBSH 9             // 512 nodes per bucket
#define NBK 196             // ceil(100000 / 512)
#define CAPL 64             // LDS slots per bucket per chunk (lambda ~21, +9.4 sigma)
#define CAPG 10240          // global bucket capacity (mean 8163, sigma ~90)
#define CHUNK 4096          // edges per bin_edges block
#define BPAD 16             // bcnt stride in ints (one counter per cache line)

typedef __hip_bfloat16 bf16;
using short8 = __attribute__((ext_vector_type(8))) short;
using f32x4  = __attribute__((ext_vector_type(4))) float;

static __device__ __forceinline__ unsigned short bf_bits(float v) {
    __hip_bfloat16 h = __float2bfloat16(v);
    return *reinterpret_cast<unsigned short*>(&h);
}

static __device__ __forceinline__ float blo(unsigned int p) {
    return __uint_as_float((p & 0xffffu) << 16);
}
static __device__ __forceinline__ float bhi(unsigned int p) {
    return __uint_as_float(p & 0xffff0000u);
}

static __device__ __forceinline__ void gld_lds16(const void* g, void* l) {
    __builtin_amdgcn_global_load_lds(
        (const __attribute__((address_space(1))) void*)g,
        (__attribute__((address_space(3))) void*)l, 16, 0, 0);
}

// ---------------- build W fragments (per layer, half-step-contiguous B-frag order) ----
// chunk layout: [l][ks][half][tl(20)][lane(64)][8], tl = s2*10 + fgroup
__global__ void build_wfrag(const float* __restrict__ W, const float* __restrict__ w_ih,
                            const float* __restrict__ w_hh, const float* __restrict__ b_ih,
                            const float* __restrict__ b_hh, bf16* __restrict__ wfrag) {
    int idx = blockIdx.x * 256 + threadIdx.x;
    if (idx >= NL * KP * NP) return;
    int j = idx % NP;
    int k = (idx / NP) % KP;
    int l = idx / (NP * KP);
    int sec = j / 160;
    int f = j - sec * 160;
    float v = 0.f;
    if (f < HID) {
        if (k < HID) {
            if (sec < 3) {  // aggr rows: fused = W_l @ w_ih^T
                const float* Wl = W + (size_t)l * HID * HID + (size_t)k * HID;
                const float* wr = w_ih + (size_t)(sec * HID + f) * HID;
                float acc = 0.f;
                for (int t = 0; t < HID; ++t) acc += Wl[t] * wr[t];
                v = acc;
            }
        } else if (k == HID) {  // bias row (A has ones here)
            v = (sec == 0) ? b_ih[f] + b_hh[f]
              : (sec == 1) ? b_ih[HID + f] + b_hh[HID + f]
              : (sec == 2) ? b_ih[2 * HID + f]
                           : b_hh[2 * HID + f];
        } else if (k >= 160 && k < 160 + HID) {  // h rows
            int kk = k - 160;
            if (sec == 0)      v = w_hh[(size_t)f * HID + kk];
            else if (sec == 1) v = w_hh[(size_t)(HID + f) * HID + kk];
            else if (sec == 3) v = w_hh[(size_t)(2 * HID + f) * HID + kk];
        }
    }
    int kstep = k >> 5, kq = (k >> 3) & 3, ki = k & 7;
    int half = sec >> 1, s2 = sec & 1;
    int fgroup = f >> 4, nl = j & 15;
    int tl = s2 * 10 + fgroup;
    int lane = kq * 16 + nl;
    size_t addr = ((((size_t)(l * KS + kstep) * 2 + half) * 20 + tl) * 64 + lane) * 8 + ki;
    wfrag[addr] = __float2bfloat16(v);
}

// ---------------- CSR build phase A: LDS-binned edge bucketing ----------------
// pack: src in bits [16:0] (NN < 2^17), dst&511 in bits [25:17]
__global__ __launch_bounds__(256)
void bin_edges(const int* __restrict__ ei, int* __restrict__ bcnt,
               unsigned int* __restrict__ bbuf) {
    __shared__ int lcnt[NBK];
    __shared__ unsigned int lstage[NBK * CAPL];
    int t = threadIdx.x;
    for (int i = t; i < NBK; i += 256) lcnt[i] = 0;
    __syncthreads();
    int e0 = blockIdx.x * CHUNK;
#pragma unroll
    for (int it = 0; it < CHUNK / 256; ++it) {
        int e = e0 + it * 256 + t;
        if (e < NE) {
            int src = ei[e], dst = ei[NE + e];
            int b = dst >> NPBSH;
            unsigned int v = (unsigned int)src | ((unsigned int)(dst & 511) << 17);
            int li = atomicAdd(&lcnt[b], 1);
            if (li < CAPL) {
                lstage[b * CAPL + li] = v;
            } else {  // rare fallback (>9 sigma): direct global append, still correct
                int gp = atomicAdd(&bcnt[b * BPAD], 1);
                if (gp < CAPG) bbuf[(size_t)b * CAPG + gp] = v;
            }
        }
    }
    __syncthreads();
    // wave-cooperative flush: contiguous chunk per bucket -> full-line writes
    int wave = t >> 6, lane = t & 63;
    for (int b = wave; b < NBK; b += 4) {
        int cnt = lcnt[b];
        if (cnt > CAPL) cnt = CAPL;
        if (cnt == 0) continue;
        int base = 0;
        if (lane == 0) base = atomicAdd(&bcnt[b * BPAD], cnt);
        base = __shfl(base, 0, 64);
        if (lane < cnt && base + lane < CAPG)
            bbuf[(size_t)b * CAPG + base + lane] = lstage[b * CAPL + lane];
    }
}

// ---------------- CSR build phase B: per-bucket histogram + scan + scatter ------
__global__ __launch_bounds__(256)
void csr_from_buckets(const int* __restrict__ bcnt, const unsigned int* __restrict__ bbuf,
                      int* __restrict__ off, int* __restrict__ csr) {
    __shared__ int hist[512];
    __shared__ int s[256];
    int b = blockIdx.x, t = threadIdx.x;
    hist[t] = 0;
    hist[256 + t] = 0;
    // global base = sum of previous bucket counts (uniform scalar loop, tiny)
    int base = 0;
    for (int i = 0; i < b; ++i) {
        int c = bcnt[i * BPAD];
        base += (c > CAPG) ? CAPG : c;
    }
    int cnt = bcnt[b * BPAD];
    if (cnt > CAPG) cnt = CAPG;
    __syncthreads();
    // pass 1: per-node histogram in LDS
    for (int i = t; i < cnt; i += 256) {
        unsigned int v = bbuf[(size_t)b * CAPG + i];
        atomicAdd(&hist[v >> 17], 1);
    }
    __syncthreads();
    // exclusive scan of 512 counters (2 per thread + Hillis-Steele over 256)
    int a0 = hist[2 * t], a1 = hist[2 * t + 1];
    int tsum = a0 + a1;
    s[t] = tsum;
    __syncthreads();
    for (int d = 1; d < 256; d <<= 1) {
        int u = (t >= d) ? s[t - d] : 0;
        __syncthreads();
        s[t] += u;
        __syncthreads();
    }
    int tb = base + s[t] - tsum;
    hist[2 * t] = tb;
    hist[2 * t + 1] = tb + a0;
    int node = (b << NPBSH) + 2 * t;
    if (node < NN) off[node] = tb;
    if (node + 1 < NN) off[node + 1] = tb + a0;
    if (b == NBK - 1 && t == 255) off[NN] = base + s[255];
    __syncthreads();
    // pass 2: scatter into contiguous ~32 KB csr window (L2-resident)
    for (int i = t; i < cnt; i += 256) {
        unsigned int v = bbuf[(size_t)b * CAPG + i];
        int p = atomicAdd(&hist[v >> 17], 1);
        csr[p] = (int)(v & 0x1FFFFu);
    }
}

// ---------------- x -> hb0 (bf16, [NNP][160], pads zeroed) ----------------
__global__ void init_h(const float* __restrict__ x, bf16* __restrict__ hb0, int nrows) {
    size_t i = (size_t)blockIdx.x * 256 + threadIdx.x;
    if (i >= (size_t)nrows * HROW) return;
    int m = (int)(i / HROW), f = (int)(i - (size_t)m * HROW);
    float v = (m < NN && f < HID) ? x[(size_t)m * HID + f] : 0.f;
    hb0[i] = __float2bfloat16(v);
}

// ---------------- fused layer: gather -> LDS Ag -> GEMM -> GRU ----------------
// 4 waves, BM=64, 2 blocks/CU (Ag 20 KB + Bs 60 KB = 80 KB exactly).
// Gather phase: wave w computes aggr for rows w*16..w*16+15 (random L3 gathers
// from hb_r) into Ag (incl. bias row k=150). A's h-part fragments (ks 5..9) are
// prefetched ONCE into 10 short8 registers before the gather (oldest in VMEM
// queue; provably landed by first use at hs=10 via the per-phase vmcnt waits).
// GEMM phase: 20 half-steps, B 3-slot LDS ring, wait vmcnt(5) -> s_barrier ->
// reads/MFMA -> stageB(hs+2) into slot (hs+2)%3 (last read at hs-1, all waves
// past it: the round-2-verified ring discipline, race-free).
__global__ __launch_bounds__(256, 2)
void layer_fused(const bf16* __restrict__ hb_r, bf16* __restrict__ hb_w,
                 const bf16* __restrict__ wfrag_l, const int* __restrict__ off,
                 const int* __restrict__ csr, float* __restrict__ h_out, int last) {
    __shared__ __align__(16) bf16 Ag[BM * HROW];      // 20 KB: aggr + bias tile
    __shared__ __align__(16) bf16 Bs[3][HS_BF];       // 60 KB: B 3-slot ring
    int tid = threadIdx.x;
    int wave = tid >> 6, lane = tid & 63;
    int mh = wave >> 1, nh = wave & 1;
    int row0 = blockIdx.x * BM;
    int col = lane & 15, q = lane >> 4;

    // ---- A h-part prefetch (K 160..319): 10 short8 registers, issued first ----
    const bf16* hrow0 = hb_r + (size_t)(row0 + mh * 32 + col) * HROW;
    const bf16* hrow1 = hrow0 + (size_t)16 * HROW;
    short8 aH0[5], aH1[5];
#pragma unroll
    for (int k5 = 0; k5 < 5; ++k5) {
        aH0[k5] = *(const short8*)(hrow0 + k5 * 32 + q * 8);
        aH1[k5] = *(const short8*)(hrow1 + k5 * 32 + q * 8);
    }

    auto stageB = [&](int hs) {
        const char* gb = (const char*)(wfrag_l + (size_t)hs * HS_BF);
        char* lb = (char*)Bs[hs % 3];
#pragma unroll
        for (int it = 0; it < 5; ++it) {
            int c = it * 256 + tid;
            gld_lds16(gb + (size_t)c * 16, lb + (size_t)c * 16);
        }
    };
    stageB(0); stageB(1);   // land during gather; drained by the __syncthreads below

    // ---- gather phase: aggr for own rows -> Ag ----
    bool tailq = lane < 11;     // dwords 64..74 cover features 128..149
    for (int i = 0; i < 16; ++i) {
        int rl = wave * 16 + i;
        int node = row0 + rl;
        int e0 = 0, e1 = 0;
        if (node < NN) { e0 = off[node]; e1 = off[node + 1]; }
        float s0 = 0.f, s1 = 0.f, t0 = 0.f, t1 = 0.f;
        int e = e0;
        for (; e + 8 <= e1; e += 8) {
            const unsigned int* r0 = (const unsigned int*)(hb_r + (size_t)csr[e]     * HROW);
            const unsigned int* r1 = (const unsigned int*)(hb_r + (size_t)csr[e + 1] * HROW);
            const unsigned int* r2 = (const unsigned int*)(hb_r + (size_t)csr[e + 2] * HROW);
            const unsigned int* r3 = (const unsigned int*)(hb_r + (size_t)csr[e + 3] * HROW);
            const unsigned int* r4 = (const unsigned int*)(hb_r + (size_t)csr[e + 4] * HROW);
            const unsigned int* r5 = (const unsigned int*)(hb_r + (size_t)csr[e + 5] * HROW);
            const unsigned int* r6 = (const unsigned int*)(hb_r + (size_t)csr[e + 6] * HROW);
            const unsigned int* r7 = (const unsigned int*)(hb_r + (size_t)csr[e + 7] * HROW);
            unsigned int p0 = r0[lane], p1 = r1[lane], p2 = r2[lane], p3 = r3[lane];
            unsigned int p4 = r4[lane], p5 = r5[lane], p6 = r6[lane], p7 = r7[lane];
            unsigned int q0 = 0, q1 = 0, q2 = 0, q3 = 0, q4 = 0, q5 = 0, q6 = 0, q7 = 0;
            if (tailq) {
                q0 = r0[64 + lane]; q1 = r1[64 + lane]; q2 = r2[64 + lane]; q3 = r3[64 + lane];
                q4 = r4[64 + lane]; q5 = r5[64 + lane]; q6 = r6[64 + lane]; q7 = r7[64 + lane];
            }
            s0 += blo(p0) + blo(p1) + blo(p2) + blo(p3) + blo(p4) + blo(p5) + blo(p6) + blo(p7);
            s1 += bhi(p0) + bhi(p1) + bhi(p2) + bhi(p3) + bhi(p4) + bhi(p5) + bhi(p6) + bhi(p7);
            t0 += blo(q0) + blo(q1) + blo(q2) + blo(q3) + blo(q4) + blo(q5) + blo(q6) + blo(q7);
            t1 += bhi(q0) + bhi(q1) + bhi(q2) + bhi(q3) + bhi(q4) + bhi(q5) + bhi(q6) + bhi(q7);
        }
        for (; e + 4 <= e1; e += 4) {
            const unsigned int* r0 = (const unsigned int*)(hb_r + (size_t)csr[e]     * HROW);
            const unsigned int* r1 = (const unsigned int*)(hb_r + (size_t)csr[e + 1] * HROW);
            const unsigned int* r2 = (const unsigned int*)(hb_r + (size_t)csr[e + 2] * HROW);
            const unsigned int* r3 = (const unsigned int*)(hb_r + (size_t)csr[e + 3] * HROW);
            unsigned int p0 = r0[lane], p1 = r1[lane], p2 = r2[lane], p3 = r3[lane];
            unsigned int q0 = 0, q1 = 0, q2 = 0, q3 = 0;
            if (tailq) { q0 = r0[64 + lane]; q1 = r1[64 + lane]; q2 = r2[64 + lane]; q3 = r3[64 + lane]; }
            s0 += blo(p0) + blo(p1) + blo(p2) + blo(p3);
            s1 += bhi(p0) + bhi(p1) + bhi(p2) + bhi(p3);
            t0 += blo(q0) + blo(q1) + blo(q2) + blo(q3);
            t1 += bhi(q0) + bhi(q1) + bhi(q2) + bhi(q3);
        }
        for (; e < e1; ++e) {
            const unsigned int* r = (const unsigned int*)(hb_r + (size_t)csr[e] * HROW);
            unsigned int p = r[lane];
            unsigned int qv = tailq ? r[64 + lane] : 0;
            s0 += blo(p); s1 += bhi(p);
            t0 += blo(qv); t1 += bhi(qv);
        }
        unsigned int* outp = (unsigned int*)(Ag + (size_t)rl * HROW);
        outp[lane] = (unsigned int)bf_bits(s0) | ((unsigned int)bf_bits(s1) << 16);
        if (tailq) outp[64 + lane] = (unsigned int)bf_bits(t0) | ((unsigned int)bf_bits(t1) << 16);
        if (lane < 5) outp[75 + lane] = (lane == 0) ? 0x00003F80u : 0u;  // bias k=150
    }
    __syncthreads();   // Ag visible; drains aH/B0/B1 (vmcnt -> 0 here)

    // ---- GEMM phase ----
    f32x4 acc[2][20];
#pragma unroll
    for (int mt = 0; mt < 2; ++mt)
#pragma unroll
        for (int t = 0; t < 20; ++t) acc[mt][t] = (f32x4){0.f, 0.f, 0.f, 0.f};

    short8 a0v, a1v;
#pragma unroll
    for (int hs = 0; hs < HSTEPS; ++hs) {
        // queue at wait (hs>=2): [sB(hs) x5, sB(hs+1) x5] -> wait oldest 5.
        // hs=0,1: queue empty (drained above) -> immediate. hs=19: drain last 5.
        if (hs < 19) asm volatile("s_waitcnt vmcnt(5)" ::: "memory");
        else         asm volatile("s_waitcnt vmcnt(0)" ::: "memory");
        __builtin_amdgcn_s_barrier();          // ALL waves' B(hs) landed (wait-then-barrier)
        __builtin_amdgcn_sched_barrier(0);

        int ks = hs >> 1, half = hs & 1;
        if (half == 0) {
            if (ks < 5) {
                a0v = *(const short8*)(Ag + (size_t)(mh * 32 + col) * HROW + ks * 32 + q * 8);
                a1v = *(const short8*)(Ag + (size_t)(mh * 32 + 16 + col) * HROW + ks * 32 + q * 8);
            } else {
                a0v = aH0[ks - 5];
                a1v = aH1[ks - 5];
            }
        }
        const bf16* Bb = Bs[hs % 3];
#pragma unroll
        for (int g = 0; g < 5; ++g) {
#pragma unroll
            for (int s2 = 0; s2 < 2; ++s2) {
                int tl = s2 * 10 + nh * 5 + g;
                short8 b = *(const short8*)(Bb + ((size_t)(tl * 64 + lane) * 8));
                int t = g * 4 + half * 2 + s2;
                acc[0][t] = __builtin_amdgcn_mfma_f32_16x16x32_bf16(a0v, b, acc[0][t], 0, 0, 0);
                acc[1][t] = __builtin_amdgcn_mfma_f32_16x16x32_bf16(a1v, b, acc[1][t], 0, 0, 0);
            }
        }
        // stage into slot (hs+2)%3: last read at hs-1, all waves past it (barrier above)
        if (hs + 2 < HSTEPS) stageB(hs + 2);
    }

    // ---- GRU epilogue: hp from global hb_r; Cs = Ag (last ds_read at hs=9) ----
    int qrow = q * 4;
    bf16* Cs = Ag;
#pragma unroll
    for (int mt = 0; mt < 2; ++mt) {
#pragma unroll
        for (int g = 0; g < 5; ++g) {
            int f = (nh * 5 + g) * 16 + col;
            if (f < HID) {
                f32x4 ar4 = acc[mt][g * 4 + 0], az = acc[mt][g * 4 + 1];
                f32x4 an = acc[mt][g * 4 + 2], ah = acc[mt][g * 4 + 3];
#pragma unroll
                for (int v = 0; v < 4; ++v) {
                    int rl = mh * 32 + mt * 16 + qrow + v;
                    float hp = __bfloat162float(hb_r[(size_t)(row0 + rl) * HROW + f]);
                    float r = 1.f / (1.f + __expf(-ar4[v]));
                    float z = 1.f / (1.f + __expf(-az[v]));
                    float n = tanhf(an[v] + r * ah[v]);
                    float ho = (1.f - z) * n + z * hp;
                    if (last) {
                        int m = row0 + rl;
                        if (m < NN) h_out[(size_t)m * HID + f] = ho;
                    } else {
                        Cs[(size_t)rl * HROW + f] = __float2bfloat16(ho);
                    }
                }
            }
        }
    }
    if (!last) {
        __syncthreads();
        // coalesced copy Cs -> hb_w rows (64 rows x 80 dwords; pads harmless: the
        // wfrag B rows for K>=310 are zero, and readers never touch pad dwords)
        const unsigned int* src = (const unsigned int*)Cs;
        unsigned int* dst = (unsigned int*)hb_w + (size_t)row0 * 80;
        for (int i = tid; i < BM * 80; i += 256) dst[i] = src[i];
    }
}

extern "C" void kernel_launch(void* const* d_in, const int* in_sizes, int n_in,
                              void* d_out, int out_size, void* d_ws, size_t ws_size,
                              hipStream_t stream) {
    const float* x      = (const float*)d_in[0];
    const float* weight = (const float*)d_in[1];
    const float* w_ih   = (const float*)d_in[2];
    const float* w_hh   = (const float*)d_in[3];
    const float* b_ih   = (const float*)d_in[4];
    const float* b_hh   = (const float*)d_in[5];
    const int*   ei     = (const int*)d_in[6];
    float* h = (float*)d_out;

    const int nblk = (NN + BM - 1) / BM;          // 1563
    const int nrows = nblk * BM;                  // 100032
    char* p = (char*)d_ws;
    auto alloc = [&](size_t bytes) { char* r = p; p += (bytes + 255) & ~255ull; return r; };
    int*  off   = (int*)alloc((size_t)(NN + 1) * 4);
    int*  csr   = (int*)alloc((size_t)NE * 4);
    int*  bcnt  = (int*)alloc((size_t)NBK * BPAD * 4);
    unsigned int* bbuf = (unsigned int*)alloc((size_t)NBK * CAPG * 4);
    bf16* wfrag = (bf16*)alloc((size_t)NL * KS * 2 * HS_BF * 2);
    bf16* hb0   = (bf16*)alloc((size_t)nrows * HROW * 2);
    bf16* hb1   = (bf16*)alloc((size_t)nrows * HROW * 2);

    hipMemsetAsync(bcnt, 0, (size_t)NBK * BPAD * 4, stream);
    build_wfrag<<<(NL * KP * NP + 255) / 256, 256, 0, stream>>>(weight, w_ih, w_hh, b_ih, b_hh, wfrag);
    bin_edges<<<(NE + CHUNK - 1) / CHUNK, 256, 0, stream>>>(ei, bcnt, bbuf);
    csr_from_buckets<<<NBK, 256, 0, stream>>>(bcnt, bbuf, off, csr);
    init_h<<<(int)(((size_t)nrows * HROW + 255) / 256), 256, 0, stream>>>(x, hb0, nrows);

    bf16* hr = hb0;
    bf16* hw = hb1;
    for (int l = 0; l < NL; ++l) {
        layer_fused<<<nblk, 256, 0, stream>>>(hr, hw, wfrag + (size_t)l * KS * 2 * HS_BF,
                                              off, csr, h, (l == NL - 1) ? 1 : 0);
        bf16* tmp = hr; hr = hw; hw = tmp;
    }
}